// Round 11
// baseline (301.006 us; speedup 1.0000x reference)
//
#include <hip/hip_runtime.h>
#include <stdint.h>

#define N_NODES 50000
#define E_EDGES 800000
#define HID 128
#define NGROUP 25000           // E_EDGES / 32
#define BE 128                 // edges per block (fallback kernel)
#define XS_STRIDE 264
#define YS_STRIDE 136
#define HS_STRIDE 132          // 66 words ≡ 2 mod 32 -> 2-way (free) A reads
#define CS_STRIDE 132          // f32 pack stage stride (16B aligned rows)
#define AGG_STRIDE_F 150016    // floats per agg replica (600064 B, 64B-aligned)

typedef unsigned short u16;
typedef unsigned char u8;
typedef __attribute__((ext_vector_type(8))) short svec8;
typedef __attribute__((ext_vector_type(16))) float fvec16;
typedef __attribute__((ext_vector_type(4))) unsigned uvec4;
typedef __attribute__((ext_vector_type(2))) unsigned uvec2;
typedef __attribute__((ext_vector_type(2))) float fvec2;

__device__ __forceinline__ float bf2f(u16 u) {
    union { unsigned int i; float f; } v; v.i = ((unsigned int)u) << 16; return v.f;
}
__device__ __forceinline__ u16 f2bf(float f) {
    union { float f; unsigned int i; } v; v.f = f;
    unsigned int u = v.i;
    return (u16)((u + 0x7fffu + ((u >> 16) & 1u)) >> 16);   // RNE
}
__device__ __forceinline__ float lo16(unsigned u) {
    union { unsigned i; float f; } v; v.i = u << 16; return v.f;
}
__device__ __forceinline__ float hi16(unsigned u) {
    union { unsigned i; float f; } v; v.i = u & 0xFFFF0000u; return v.f;
}
__device__ __forceinline__ float silu_f(float x) {
    return x * __builtin_amdgcn_rcpf(1.0f + __expf(-x));
}
// 1-transcendental silu approx (round-7, perf-neutral, accuracy verified absmax 0.0078):
// x*(0.5 + 0.5*x/(1+|x|)). phi-path attenuation (W3 a~2e-4, /100) bounds output impact
// ~3e-5 << bf16 ulp 0.0039; y is fp8-quantized anyway.
__device__ __forceinline__ float silu_fast(float x) {
    float ax = __builtin_fabsf(x);
    return x * (0.5f + 0.5f * x * __builtin_amdgcn_rcpf(1.0f + ax));
}
__device__ __forceinline__ float ldf(const void* p, size_t i, int is_bf) {
    return is_bf ? bf2f(((const u16*)p)[i]) : ((const float*)p)[i];
}
__device__ __forceinline__ int ldi(const void* p, size_t i, int is_i64) {
    return is_i64 ? ((const int*)p)[2 * i] : ((const int*)p)[i];
}

// ---- inline dtype detection (wave-uniform via ballot) ----
__device__ __forceinline__ int detect_bf_w(const void* p) {
    unsigned u = ((const u16*)p)[2 * (threadIdx.x & 63)];
    unsigned e = (u >> 7) & 0xFFu;
    unsigned long long m = __ballot(e >= 100u && e <= 140u);
    return __popcll(m) >= 48;
}
__device__ __forceinline__ int detect_i64_w(const void* eidx) {
    unsigned long long m = __ballot(((const int*)eidx)[2 * (threadIdx.x & 63) + 1] == 0);
    return __popcll(m) >= 48;
}

// ---- W transpose + w1l(bf16) + agg-replica zeroing (memset folded in) ----
__global__ void transpose_w(const void* __restrict__ W1, const void* __restrict__ W2,
                            u16* __restrict__ W1t, u16* __restrict__ W2t,
                            u16* __restrict__ w1lb, float* __restrict__ agg, int nzero) {
    const int is_bf = detect_bf_w(W1);
    int n = blockIdx.x;        // 0..127 output column
    int k = threadIdx.x;       // 0..255
    W1t[n * 256 + k] = f2bf(ldf(W1, (size_t)k * 128 + n, is_bf));
    if (k < 128) W2t[n * 128 + k] = f2bf(ldf(W2, (size_t)k * 128 + n, is_bf));
    if (n == 0 && k < 128) w1lb[k] = f2bf(ldf(W1, (size_t)256 * 128 + k, is_bf));
    for (int i = blockIdx.x * 256 + k; i < nzero; i += 128 * 256) agg[i] = 0.0f;
}

// ---- precompute P[node][0:128]=fp8(h@W1a+b1), P[node][128:256]=fp8(h@W1b) ----
// 64-node blocks: LDS union 33.8 KB -> 4 blocks/CU.
__global__ __launch_bounds__(256) void precompute_p(
    const void* __restrict__ h, const void* __restrict__ b1,
    const u16* __restrict__ W1t, u8* __restrict__ P)
{
    __shared__ __align__(16) union SMem {
        u16 Hs[64 * HS_STRIDE];         // 16.9 KB
        float Cs[64 * CS_STRIDE];       // 33.8 KB
    } sm;
    const int tid = threadIdx.x;
    const int is_bf = detect_bf_w(h);
    const int base = blockIdx.x * 64;
    {
        const int rr = tid >> 5, c = tid & 31;
        #pragma unroll
        for (int it = 0; it < 8; ++it) {
            int row = it * 8 + rr;
            int node = base + row; if (node > N_NODES - 1) node = N_NODES - 1;
            u16* dst = &sm.Hs[row * HS_STRIDE + c * 4];
            if (is_bf) {
                *(uint2*)dst = *(const uint2*)((const u16*)h + (size_t)node * HID + c * 4);
            } else {
                float4 v = *(const float4*)((const float*)h + (size_t)node * HID + c * 4);
                uint2 w;
                w.x = (unsigned)f2bf(v.x) | ((unsigned)f2bf(v.y) << 16);
                w.y = (unsigned)f2bf(v.z) | ((unsigned)f2bf(v.w) << 16);
                *(uint2*)dst = w;
            }
        }
    }
    __syncthreads();
    const int lane = tid & 63, wv = tid >> 6, l31 = lane & 31, hi = lane >> 5;
    const int mb = (wv & 1) * 32;        // row block within the 64 nodes
    const int tb = (wv >> 1) * 4;        // strip base: 0 (half0) or 4 (half1)
    fvec16 acc[4] = {};
    for (int ks = 0; ks < 8; ++ks) {
        const int kk = ks * 16 + hi * 8;
        svec8 af = *(const svec8*)(&sm.Hs[(mb + l31) * HS_STRIDE + kk]);
        #pragma unroll
        for (int tt = 0; tt < 4; ++tt) {
            const int t = tb + tt;
            const int n = t * 32 + l31;
            const u16* bp = (t < 4) ? (W1t + n * 256 + kk)
                                    : (W1t + (n - 128) * 256 + 128 + kk);
            svec8 bf = *(const svec8*)bp;
            acc[tt] = __builtin_amdgcn_mfma_f32_32x32x16_bf16(af, bf, acc[tt], 0, 0, 0);
        }
    }
    __syncthreads();                 // all waves done reading Hs before Cs overwrite
    #pragma unroll
    for (int half = 0; half < 2; ++half) {
        if ((wv >> 1) == half) {
            #pragma unroll
            for (int tt = 0; tt < 4; ++tt) {
                const int colh = tt * 32 + l31;               // col within 128-wide half
                const float bias = (half == 0) ? ldf(b1, colh, is_bf) : 0.0f;
                #pragma unroll
                for (int r = 0; r < 16; ++r) {
                    int m = (r & 3) + 8 * (r >> 2) + 4 * hi;
                    sm.Cs[(mb + m) * CS_STRIDE + colh] = acc[tt][r] + bias;
                }
            }
        }
        __syncthreads();
        #pragma unroll
        for (int i = 0; i < 2; ++i) {
            int row = i * 32 + (tid >> 3);
            int node = base + row;
            if (node < N_NODES) {
                const float* src = &sm.Cs[row * CS_STRIDE + (tid & 7) * 16];
                uvec4 outv;
                #pragma unroll
                for (int d = 0; d < 4; ++d) {
                    int w = __builtin_amdgcn_cvt_pk_fp8_f32(src[d * 4 + 0], src[d * 4 + 1], 0, false);
                    w     = __builtin_amdgcn_cvt_pk_fp8_f32(src[d * 4 + 2], src[d * 4 + 3], w, true);
                    outv[d] = (unsigned)w;
                }
                *(uvec4*)(P + (size_t)node * 256 + half * 128 + (tid & 7) * 16) = outv;
            }
        }
        __syncthreads();             // pack reads done before next half's Cs overwrite
    }
}

// ---- edge kernel: REGISTER-prefetch fp8 P -> add+silu -> fp8 W2 MFMA -> phi -> scatter ----
// Round-11: __launch_bounds__(256,4). Round-10's fixed 1536-block grid left occupancy AND
// dur unchanged (26.6%, 117us) -> residency is hard-pinned at 2 blocks/CU. The only
// consistent explanation across rounds 4-10: the unified-file allocation equals the
// waves-per-eu BUDGET (bounds(256,2) -> 256 regs/wave granule -> 2 waves/SIMD always),
// with reported VGPR_Count (80) excluding the AGPR/padding share. (256,4) halves the
// budget to 128; current slim demand (~96-110: pv32+af16+acc16+s16+misc) FITS now --
// round-1's (256,4) spill was the old ~160-reg structure. If it fits: 4 waves/SIMD,
// first real occupancy doubling. Grid 1024 (4/CU). Schedule unchanged from round 8.
__global__ __launch_bounds__(256, 4) void egnn_edge_p(
    const u8* __restrict__ P, const void* __restrict__ coord_diff,
    const void* __restrict__ edge_attr, const void* __restrict__ edge_index,
    const u16* __restrict__ w1lb, const void* __restrict__ b2,
    const void* __restrict__ W3, const u16* __restrict__ W2t,
    float* __restrict__ agg, int rep_mask)
{
    __shared__ __align__(16) u8  W2f8[16384];  // frag-ordered W2 (16 KB fp8), K-chunk-permuted
    __shared__ __align__(16) u16 w1ls[128];    // last W1 row (256 B)
    const int tid = threadIdx.x;
    #pragma unroll
    for (int i = 0; i < 8; ++i) {              // stage: f = t*512+ks*64+fh*32+fl, dst=f*8 bytes
        int f = i * 256 + tid;
        int t = f >> 9, ks = (f >> 6) & 7, fh = (f >> 5) & 1, fl = f & 31;
        // chunk for (ks,fh) is c = fh*8 + ks  (contiguous-per-lane K remap)
        svec8 v = *(const svec8*)(W2t + (t * 32 + fl) * 128 + fh * 64 + ks * 8);
        float x0 = bf2f((u16)v[0]), x1 = bf2f((u16)v[1]), x2 = bf2f((u16)v[2]), x3 = bf2f((u16)v[3]);
        float x4 = bf2f((u16)v[4]), x5 = bf2f((u16)v[5]), x6 = bf2f((u16)v[6]), x7 = bf2f((u16)v[7]);
        int w0 = __builtin_amdgcn_cvt_pk_fp8_f32(x0, x1, 0, false);
        w0     = __builtin_amdgcn_cvt_pk_fp8_f32(x2, x3, w0, true);
        int w1 = __builtin_amdgcn_cvt_pk_fp8_f32(x4, x5, 0, false);
        w1     = __builtin_amdgcn_cvt_pk_fp8_f32(x6, x7, w1, true);
        uvec2 wv2; wv2[0] = (unsigned)w0; wv2[1] = (unsigned)w1;
        *(uvec2*)(&W2f8[f * 8]) = wv2;
    }
    if (tid < 16) *(uvec4*)(&w1ls[tid * 8]) = *(const uvec4*)(w1lb + tid * 8);
    const int is_bf = detect_bf_w(edge_attr);
    const int is_i64 = detect_i64_w(edge_index);
    const int lane = tid & 63, wv = tid >> 6, l31 = lane & 31, hi = lane >> 5;

    float b2c[4], w3c[4];
    #pragma unroll
    for (int t = 0; t < 4; ++t) {
        int c = t * 32 + l31;
        b2c[t] = ldf(b2, c, is_bf);
        w3c[t] = ldf(W3, c, is_bf);
    }
    __syncthreads();                           // last barrier; main loop is wave-autonomous

    float* const aggw = agg + (size_t)(blockIdx.x & rep_mask) * AGG_STRIDE_F;

    // static output-row mapping for the tree-reduce result
    const int b0 = l31 & 1, bb1 = (l31 >> 1) & 1, bb2 = (l31 >> 2) & 1, bb3 = (l31 >> 3) & 1;
    const int rr = (b0 << 3) | (bb1 << 2) | (bb2 << 1) | bb3;   // bitrev4(l31&15)
    const int em = (rr & 3) + 8 * (rr >> 2) + 4 * hi;           // C-layout row within group

    const int wid = blockIdx.x * 4 + wv, nw = gridDim.x * 4;
    int g = wid;
    uvec4 pv1[4], pv2[4];
    int rowN = 0, colN = 0; float eaN = 0.0f, ea_cur = 0.0f;
    if (g < NGROUP) {   // prologue: idx(g) -> gather(g) into regs -> idx(g+nw)
        const int e = g * 32 + l31;
        const int row0 = ldi(edge_index, (size_t)e, is_i64);
        const int col0 = ldi(edge_index, (size_t)E_EDGES + e, is_i64);
        ea_cur = ldf(edge_attr, (size_t)e, is_bf);
        const u8* pr = P + (size_t)row0 * 256 + hi * 64;
        const u8* pc = P + (size_t)col0 * 256 + 128 + hi * 64;
        #pragma unroll
        for (int j = 0; j < 4; ++j) pv1[j] = *(const uvec4*)(pr + j * 16);
        #pragma unroll
        for (int j = 0; j < 4; ++j) pv2[j] = *(const uvec4*)(pc + j * 16);
        const int gn = g + nw;
        if (gn < NGROUP) {
            const int en = gn * 32 + l31;
            rowN = ldi(edge_index, (size_t)en, is_i64);
            colN = ldi(edge_index, (size_t)E_EDGES + en, is_i64);
            eaN  = ldf(edge_attr, (size_t)en, is_bf);
        }
    }
    while (g < NGROUP) {
        const int gn = g + nw;
        // ---- 1. convert pv -> af fp8 (pv registers die here) ----
        long long af8[8];
        #pragma unroll
        for (int ks = 0; ks < 8; ++ks) {
            const unsigned a0 = pv1[ks >> 1][(ks & 1) * 2];
            const unsigned a1 = pv1[ks >> 1][(ks & 1) * 2 + 1];
            const unsigned c0 = pv2[ks >> 1][(ks & 1) * 2];
            const unsigned c1 = pv2[ks >> 1][(ks & 1) * 2 + 1];
            float q1[8], q2[8];
            {
                fvec2 t0 = __builtin_amdgcn_cvt_pk_f32_fp8((int)a0, false);
                fvec2 t1 = __builtin_amdgcn_cvt_pk_f32_fp8((int)a0, true);
                fvec2 t2 = __builtin_amdgcn_cvt_pk_f32_fp8((int)a1, false);
                fvec2 t3 = __builtin_amdgcn_cvt_pk_f32_fp8((int)a1, true);
                q1[0] = t0[0]; q1[1] = t0[1]; q1[2] = t1[0]; q1[3] = t1[1];
                q1[4] = t2[0]; q1[5] = t2[1]; q1[6] = t3[0]; q1[7] = t3[1];
                fvec2 s0 = __builtin_amdgcn_cvt_pk_f32_fp8((int)c0, false);
                fvec2 s1 = __builtin_amdgcn_cvt_pk_f32_fp8((int)c0, true);
                fvec2 s2 = __builtin_amdgcn_cvt_pk_f32_fp8((int)c1, false);
                fvec2 s3 = __builtin_amdgcn_cvt_pk_f32_fp8((int)c1, true);
                q2[0] = s0[0]; q2[1] = s0[1]; q2[2] = s1[0]; q2[3] = s1[1];
                q2[4] = s2[0]; q2[5] = s2[1]; q2[6] = s3[0]; q2[7] = s3[1];
            }
            const uvec4 wl = *(const uvec4*)(&w1ls[(hi * 8 + ks) * 8]);
            float y[8];
            #pragma unroll
            for (int p = 0; p < 4; ++p) {
                const unsigned uw = wl[p];
                float xl = q1[2 * p]     + q2[2 * p]     + ea_cur * lo16(uw);
                float xh = q1[2 * p + 1] + q2[2 * p + 1] + ea_cur * hi16(uw);
                y[2 * p] = silu_fast(xl); y[2 * p + 1] = silu_fast(xh);
            }
            int w0 = __builtin_amdgcn_cvt_pk_fp8_f32(y[0], y[1], 0, false);
            w0     = __builtin_amdgcn_cvt_pk_fp8_f32(y[2], y[3], w0, true);
            int w1 = __builtin_amdgcn_cvt_pk_fp8_f32(y[4], y[5], 0, false);
            w1     = __builtin_amdgcn_cvt_pk_fp8_f32(y[6], y[7], w1, true);
            af8[ks] = (long long)(((unsigned long long)(unsigned)w1 << 32) | (unsigned)w0);
        }
        // ---- 2. issue next group's gathers into the SAME pv regs (pinned placement) ----
        __builtin_amdgcn_sched_barrier(0);
        if (gn < NGROUP) {
            const u8* pr = P + (size_t)rowN * 256 + hi * 64;
            const u8* pc = P + (size_t)colN * 256 + 128 + hi * 64;
            #pragma unroll
            for (int j = 0; j < 4; ++j) pv1[j] = *(const uvec4*)(pr + j * 16);
            #pragma unroll
            for (int j = 0; j < 4; ++j) pv2[j] = *(const uvec4*)(pc + j * 16);
        }
        __builtin_amdgcn_sched_barrier(0);
        // ---- 3. idx prefetch for g+2nw and scatter-side loads for current g ----
        int rowN2 = 0, colN2 = 0; float eaN2 = 0.0f;
        if (gn + nw < NGROUP) {
            const int en = (gn + nw) * 32 + l31;
            rowN2 = ldi(edge_index, (size_t)en, is_i64);
            colN2 = ldi(edge_index, (size_t)E_EDGES + en, is_i64);
            eaN2  = ldf(edge_attr, (size_t)en, is_bf);
        }
        const int eg = g * 32 + em;
        const int r2 = ldi(edge_index, (size_t)eg, is_i64);
        float cd0, cd1;
        if (l31 < 16) {
            cd0 = ldf(coord_diff, (size_t)eg * 3 + 0, is_bf);
            cd1 = ldf(coord_diff, (size_t)eg * 3 + 1, is_bf);
        } else {
            cd0 = ldf(coord_diff, (size_t)eg * 3 + 2, is_bf);
            cd1 = 0.0f;
        }
        // ---- 4. fp8 W2 MFMA + silu + W3 dot, per output strip ----
        float s[16];
        #pragma unroll
        for (int r = 0; r < 16; ++r) s[r] = 0.0f;
        #pragma unroll
        for (int t = 0; t < 4; ++t) {          // per-strip acc: 16 regs
            fvec16 acc = {};
            #pragma unroll
            for (int ks = 0; ks < 8; ++ks) {
                union { uvec2 u; long long l; } bu;
                bu.u = *(const uvec2*)(&W2f8[((t * 8 + ks) * 2 + hi) * 256 + l31 * 8]);
                acc = __builtin_amdgcn_mfma_f32_32x32x16_fp8_fp8(af8[ks], bu.l, acc, 0, 0, 0);
            }
            #pragma unroll
            for (int r = 0; r < 16; ++r)
                s[r] += silu_fast(acc[r] + b2c[t]) * w3c[t];
        }
        // ---- 5. halving-tree reduce: 16 rows over 32 lanes in 31 shuffles ----
        #pragma unroll
        for (int r = 0; r < 16; ++r) s[r] += __shfl_xor(s[r], 1);
        float w4[8];
        #pragma unroll
        for (int j = 0; j < 8; ++j) w4[j] = b0 ? s[j + 8] : s[j];
        #pragma unroll
        for (int j = 0; j < 8; ++j) w4[j] += __shfl_xor(w4[j], 2);
        float x4[4];
        #pragma unroll
        for (int j = 0; j < 4; ++j) x4[j] = bb1 ? w4[j + 4] : w4[j];
        #pragma unroll
        for (int j = 0; j < 4; ++j) x4[j] += __shfl_xor(x4[j], 4);
        float y2[2];
        y2[0] = bb2 ? x4[2] : x4[0];
        y2[1] = bb2 ? x4[3] : x4[1];
        y2[0] += __shfl_xor(y2[0], 8);
        y2[1] += __shfl_xor(y2[1], 8);
        float z = bb3 ? y2[1] : y2[0];
        z += __shfl_xor(z, 16);
        // ---- 6. scatter to XCD-private replica ----
        if (l31 < 16) {
            atomicAdd(&aggw[r2 * 3 + 0], cd0 * z);
            atomicAdd(&aggw[r2 * 3 + 1], cd1 * z);
        } else {
            atomicAdd(&aggw[r2 * 3 + 2], cd0 * z);
        }
        // ---- rotate pipeline state ----
        g = gn; ea_cur = eaN;
        rowN = rowN2; colN = colN2; eaN = eaN2;
    }
}

// ================= fallback (verified) when ws too small: writes replica 0 =================
__global__ __launch_bounds__(256, 2) void egnn_edge_kernel(
    const void* __restrict__ h, const void* __restrict__ coord_diff,
    const void* __restrict__ edge_attr, const void* __restrict__ edge_index,
    const void* __restrict__ W1, const void* __restrict__ b1,
    const void* __restrict__ b2, const void* __restrict__ W3,
    const u16* __restrict__ W1t, const u16* __restrict__ W2t,
    float* __restrict__ agg)
{
    __shared__ __align__(16) u16 Xs[BE * XS_STRIDE];
    __shared__ int   rows_s[BE];
    __shared__ int   cols_s[BE];
    __shared__ float ea_s[BE];
    __shared__ float b1_s[HID], b2_s[HID], w1l_s[HID], w3_s[HID];

    const int tid = threadIdx.x;
    const int e0  = blockIdx.x * BE;
    const int is_bf  = detect_bf_w(h);
    const int is_i64 = detect_i64_w(edge_index);

    if (tid < BE) {
        rows_s[tid] = ldi(edge_index, (size_t)(e0 + tid), is_i64);
        cols_s[tid] = ldi(edge_index, (size_t)(E_EDGES + e0 + tid), is_i64);
        ea_s[tid]   = ldf(edge_attr, (size_t)(e0 + tid), is_bf);
    }
    if (tid < HID) {
        b1_s[tid]  = ldf(b1, tid, is_bf);
        b2_s[tid]  = ldf(b2, tid, is_bf);
        w1l_s[tid] = ldf(W1, (size_t)256 * 128 + tid, is_bf);
        w3_s[tid]  = ldf(W3, tid, is_bf);
    }
    __syncthreads();
    {
        const int gg = tid >> 4, c = tid & 15;
        #pragma unroll
        for (int it = 0; it < 16; ++it) {
            int hr = it * 16 + gg;
            int e = hr >> 1, half = hr & 1;
            int src = half ? cols_s[e] : rows_s[e];
            svec8 v;
            if (is_bf) {
                v = *(const svec8*)((const u16*)h + (size_t)src * HID + c * 8);
            } else {
                const float* hf = (const float*)h + (size_t)src * HID + c * 8;
                float4 va = *(const float4*)hf;
                float4 vb = *(const float4*)(hf + 4);
                v[0] = (short)f2bf(va.x); v[1] = (short)f2bf(va.y);
                v[2] = (short)f2bf(va.z); v[3] = (short)f2bf(va.w);
                v[4] = (short)f2bf(vb.x); v[5] = (short)f2bf(vb.y);
                v[6] = (short)f2bf(vb.z); v[7] = (short)f2bf(vb.w);
            }
            *(svec8*)(&Xs[e * XS_STRIDE + half * 128 + c * 8]) = v;
        }
    }
    __syncthreads();
    const int lane = tid & 63;
    const int wv   = tid >> 6;
    const int l31  = lane & 31, hi = lane >> 5;
    const int col  = wv * 32 + l31;

    fvec16 acc[4] = {};
    for (int ks = 0; ks < 16; ++ks) {
        const int kk = ks * 16 + hi * 8;
        svec8 bfrag = *(const svec8*)(W1t + col * 256 + kk);
        #pragma unroll
        for (int mt = 0; mt < 4; ++mt) {
            svec8 afrag = *(const svec8*)(&Xs[(mt * 32 + l31) * XS_STRIDE + kk]);
            acc[mt] = __builtin_amdgcn_mfma_f32_32x32x16_bf16(afrag, bfrag, acc[mt], 0, 0, 0);
        }
    }
    __syncthreads();
    u16* Ys = Xs;
    #pragma unroll
    for (int mt = 0; mt < 4; ++mt)
        #pragma unroll
        for (int r = 0; r < 16; ++r) {
            int row = mt * 32 + (r & 3) + 8 * (r >> 2) + 4 * hi;
            float v = acc[mt][r] + ea_s[row] * w1l_s[col] + b1_s[col];
            Ys[row * YS_STRIDE + col] = f2bf(silu_f(v));
        }
    __syncthreads();
    fvec16 acc2[4] = {};
    for (int ks = 0; ks < 8; ++ks) {
        const int kk = ks * 16 + hi * 8;
        svec8 bfrag = *(const svec8*)(W2t + col * 128 + kk);
        #pragma unroll
        for (int mt = 0; mt < 4; ++mt) {
            svec8 afrag = *(const svec8*)(&Ys[(mt * 32 + l31) * YS_STRIDE + kk]);
            acc2[mt] = __builtin_amdgcn_mfma_f32_32x32x16_bf16(afrag, bfrag, acc2[mt], 0, 0, 0);
        }
    }
    __syncthreads();
    #pragma unroll
    for (int mt = 0; mt < 4; ++mt)
        #pragma unroll
        for (int r = 0; r < 16; ++r) {
            int row = mt * 32 + (r & 3) + 8 * (r >> 2) + 4 * hi;
            float v = acc2[mt][r] + b2_s[col];
            Ys[row * YS_STRIDE + col] = f2bf(silu_f(v));
        }
    __syncthreads();
    if (tid < BE) {
        const int e = tid;
        float phi = 0.0f;
        #pragma unroll
        for (int j = 0; j < 16; ++j) {
            svec8 x = *(const svec8*)(&Ys[e * YS_STRIDE + j * 8]);
            #pragma unroll
            for (int t = 0; t < 8; ++t)
                phi += bf2f((u16)x[t]) * w3_s[j * 8 + t];
        }
        const size_t ei = (size_t)(e0 + e);
        const int r = rows_s[e];
        atomicAdd(&agg[r * 3 + 0], ldf(coord_diff, ei * 3 + 0, is_bf) * phi);
        atomicAdd(&agg[r * 3 + 1], ldf(coord_diff, ei * 3 + 1, is_bf) * phi);
        atomicAdd(&agg[r * 3 + 2], ldf(coord_diff, ei * 3 + 2, is_bf) * phi);
    }
}

// ---- finalize: out = coord + (sum of replicas)/100, written in input float dtype ----
__global__ void finalize_kernel(const void* __restrict__ coord,
                                const float* __restrict__ agg,
                                void* __restrict__ out, int rep) {
    const int is_bf = detect_bf_w(coord);
    int i = blockIdx.x * blockDim.x + threadIdx.x;
    if (i < N_NODES * 3) {
        float a = 0.0f;
        for (int k = 0; k < rep; ++k) a += agg[(size_t)k * AGG_STRIDE_F + i];
        float v = ldf(coord, i, is_bf) + a * 0.01f;
        if (is_bf) ((u16*)out)[i] = f2bf(v);
        else       ((float*)out)[i] = v;
    }
}

extern "C" void kernel_launch(void* const* d_in, const int* in_sizes, int n_in,
                              void* d_out, int out_size, void* d_ws, size_t ws_size,
                              hipStream_t stream) {
    const void* h          = d_in[0];
    const void* coord      = d_in[1];
    const void* coord_diff = d_in[2];
    // d_in[3] = coord_cross (unused)
    const void* edge_attr  = d_in[4];
    const void* edge_index = d_in[5];
    const void* W1 = d_in[6];
    const void* b1 = d_in[7];
    const void* W2 = d_in[8];
    const void* b2 = d_in[9];
    const void* W3 = d_in[10];

    const size_t P_BYTES = (size_t)N_NODES * 256;           // 12,800,000
    const size_t NEED8 = 8ull * 600064 + 98560 + P_BYTES;   // ~17.7 MB
    const size_t NEED1 = 1ull * 600064 + 98560 + P_BYTES;   // ~13.5 MB

    const int rep = (ws_size >= NEED8) ? 8 : 1;
    char* ws    = (char*)d_ws;
    float* agg  = (float*)ws;                               // rep x 600064 B
    size_t a0   = (size_t)rep * 600064;
    u16* W1t    = (u16*)(ws + a0);                          // 65536 B
    u16* W2t    = (u16*)(ws + a0 + 65536);                  // 32768 B
    u16* w1lb   = (u16*)(ws + a0 + 98304);                  // 256 B
    u8* P       = (u8*)(ws + a0 + 98560);                   // 12,800,000 B

    // transpose_w also zeroes all agg replicas and self-detects dtype
    transpose_w<<<dim3(128), dim3(256), 0, stream>>>(W1, W2, W1t, W2t, w1lb, agg,
                                                     rep * AGG_STRIDE_F);

    if (ws_size >= (rep == 8 ? NEED8 : NEED1)) {
        precompute_p<<<dim3((N_NODES + 63) / 64), dim3(256), 0, stream>>>(
            h, b1, W1t, P);
        // 1024 blocks = 4/CU target under the (256,4) 128-reg budget
        egnn_edge_p<<<dim3(1024), dim3(256), 0, stream>>>(
            P, coord_diff, edge_attr, edge_index, w1lb, b2, W3, W2t, agg, rep - 1);
    } else {
        egnn_edge_kernel<<<dim3(E_EDGES / BE), dim3(256), 0, stream>>>(
            h, coord_diff, edge_attr, edge_index, W1, b1, b2, W3, W1t, W2t, agg);
    }
    finalize_kernel<<<dim3((N_NODES * 3 + 255) / 256), dim3(256), 0, stream>>>(
        coord, agg, d_out, rep);
}

// Round 12
// 239.000 us; speedup vs baseline: 1.2594x; 1.2594x over previous
//
#include <hip/hip_runtime.h>
#include <stdint.h>

#define N_NODES 50000
#define E_EDGES 800000
#define HID 128
#define NGROUP 25000           // E_EDGES / 32
#define BE 128                 // edges per block (fallback kernel)
#define XS_STRIDE 264
#define YS_STRIDE 136
#define HS_STRIDE 132          // 66 words ≡ 2 mod 32 -> 2-way (free) A reads
#define CS_STRIDE 132          // f32 pack stage stride (16B aligned rows)
#define AGG_STRIDE_F 150016    // floats per agg replica (600064 B, 64B-aligned)

typedef unsigned short u16;
typedef unsigned char u8;
typedef __attribute__((ext_vector_type(8))) short svec8;
typedef __attribute__((ext_vector_type(16))) float fvec16;
typedef __attribute__((ext_vector_type(4))) unsigned uvec4;
typedef __attribute__((ext_vector_type(2))) unsigned uvec2;
typedef __attribute__((ext_vector_type(2))) float fvec2;

__device__ __forceinline__ float bf2f(u16 u) {
    union { unsigned int i; float f; } v; v.i = ((unsigned int)u) << 16; return v.f;
}
__device__ __forceinline__ u16 f2bf(float f) {
    union { float f; unsigned int i; } v; v.f = f;
    unsigned int u = v.i;
    return (u16)((u + 0x7fffu + ((u >> 16) & 1u)) >> 16);   // RNE
}
__device__ __forceinline__ float lo16(unsigned u) {
    union { unsigned i; float f; } v; v.i = u << 16; return v.f;
}
__device__ __forceinline__ float hi16(unsigned u) {
    union { unsigned i; float f; } v; v.i = u & 0xFFFF0000u; return v.f;
}
__device__ __forceinline__ float silu_f(float x) {
    return x * __builtin_amdgcn_rcpf(1.0f + __expf(-x));
}
// 1-transcendental silu approx (round-7, perf-neutral, accuracy verified absmax 0.0078):
// x*(0.5 + 0.5*x/(1+|x|)). phi-path attenuation (W3 a~2e-4, /100) bounds output impact
// ~3e-5 << bf16 ulp 0.0039; y is fp8-quantized anyway.
__device__ __forceinline__ float silu_fast(float x) {
    float ax = __builtin_fabsf(x);
    return x * (0.5f + 0.5f * x * __builtin_amdgcn_rcpf(1.0f + ax));
}
__device__ __forceinline__ float ldf(const void* p, size_t i, int is_bf) {
    return is_bf ? bf2f(((const u16*)p)[i]) : ((const float*)p)[i];
}
__device__ __forceinline__ int ldi(const void* p, size_t i, int is_i64) {
    return is_i64 ? ((const int*)p)[2 * i] : ((const int*)p)[i];
}

// ---- inline dtype detection (wave-uniform via ballot) ----
__device__ __forceinline__ int detect_bf_w(const void* p) {
    unsigned u = ((const u16*)p)[2 * (threadIdx.x & 63)];
    unsigned e = (u >> 7) & 0xFFu;
    unsigned long long m = __ballot(e >= 100u && e <= 140u);
    return __popcll(m) >= 48;
}
__device__ __forceinline__ int detect_i64_w(const void* eidx) {
    unsigned long long m = __ballot(((const int*)eidx)[2 * (threadIdx.x & 63) + 1] == 0);
    return __popcll(m) >= 48;
}

// ---- W transpose + w1l(bf16) + agg-replica zeroing (memset folded in) ----
__global__ void transpose_w(const void* __restrict__ W1, const void* __restrict__ W2,
                            u16* __restrict__ W1t, u16* __restrict__ W2t,
                            u16* __restrict__ w1lb, float* __restrict__ agg, int nzero) {
    const int is_bf = detect_bf_w(W1);
    int n = blockIdx.x;        // 0..127 output column
    int k = threadIdx.x;       // 0..255
    W1t[n * 256 + k] = f2bf(ldf(W1, (size_t)k * 128 + n, is_bf));
    if (k < 128) W2t[n * 128 + k] = f2bf(ldf(W2, (size_t)k * 128 + n, is_bf));
    if (n == 0 && k < 128) w1lb[k] = f2bf(ldf(W1, (size_t)256 * 128 + k, is_bf));
    for (int i = blockIdx.x * 256 + k; i < nzero; i += 128 * 256) agg[i] = 0.0f;
}

// ---- precompute P[node][0:128]=fp8(h@W1a+b1), P[node][128:256]=fp8(h@W1b) ----
// 64-node blocks: LDS union 33.8 KB -> 4 blocks/CU.
__global__ __launch_bounds__(256) void precompute_p(
    const void* __restrict__ h, const void* __restrict__ b1,
    const u16* __restrict__ W1t, u8* __restrict__ P)
{
    __shared__ __align__(16) union SMem {
        u16 Hs[64 * HS_STRIDE];         // 16.9 KB
        float Cs[64 * CS_STRIDE];       // 33.8 KB
    } sm;
    const int tid = threadIdx.x;
    const int is_bf = detect_bf_w(h);
    const int base = blockIdx.x * 64;
    {
        const int rr = tid >> 5, c = tid & 31;
        #pragma unroll
        for (int it = 0; it < 8; ++it) {
            int row = it * 8 + rr;
            int node = base + row; if (node > N_NODES - 1) node = N_NODES - 1;
            u16* dst = &sm.Hs[row * HS_STRIDE + c * 4];
            if (is_bf) {
                *(uint2*)dst = *(const uint2*)((const u16*)h + (size_t)node * HID + c * 4);
            } else {
                float4 v = *(const float4*)((const float*)h + (size_t)node * HID + c * 4);
                uint2 w;
                w.x = (unsigned)f2bf(v.x) | ((unsigned)f2bf(v.y) << 16);
                w.y = (unsigned)f2bf(v.z) | ((unsigned)f2bf(v.w) << 16);
                *(uint2*)dst = w;
            }
        }
    }
    __syncthreads();
    const int lane = tid & 63, wv = tid >> 6, l31 = lane & 31, hi = lane >> 5;
    const int mb = (wv & 1) * 32;        // row block within the 64 nodes
    const int tb = (wv >> 1) * 4;        // strip base: 0 (half0) or 4 (half1)
    fvec16 acc[4] = {};
    for (int ks = 0; ks < 8; ++ks) {
        const int kk = ks * 16 + hi * 8;
        svec8 af = *(const svec8*)(&sm.Hs[(mb + l31) * HS_STRIDE + kk]);
        #pragma unroll
        for (int tt = 0; tt < 4; ++tt) {
            const int t = tb + tt;
            const int n = t * 32 + l31;
            const u16* bp = (t < 4) ? (W1t + n * 256 + kk)
                                    : (W1t + (n - 128) * 256 + 128 + kk);
            svec8 bf = *(const svec8*)bp;
            acc[tt] = __builtin_amdgcn_mfma_f32_32x32x16_bf16(af, bf, acc[tt], 0, 0, 0);
        }
    }
    __syncthreads();                 // all waves done reading Hs before Cs overwrite
    #pragma unroll
    for (int half = 0; half < 2; ++half) {
        if ((wv >> 1) == half) {
            #pragma unroll
            for (int tt = 0; tt < 4; ++tt) {
                const int colh = tt * 32 + l31;               // col within 128-wide half
                const float bias = (half == 0) ? ldf(b1, colh, is_bf) : 0.0f;
                #pragma unroll
                for (int r = 0; r < 16; ++r) {
                    int m = (r & 3) + 8 * (r >> 2) + 4 * hi;
                    sm.Cs[(mb + m) * CS_STRIDE + colh] = acc[tt][r] + bias;
                }
            }
        }
        __syncthreads();
        #pragma unroll
        for (int i = 0; i < 2; ++i) {
            int row = i * 32 + (tid >> 3);
            int node = base + row;
            if (node < N_NODES) {
                const float* src = &sm.Cs[row * CS_STRIDE + (tid & 7) * 16];
                uvec4 outv;
                #pragma unroll
                for (int d = 0; d < 4; ++d) {
                    int w = __builtin_amdgcn_cvt_pk_fp8_f32(src[d * 4 + 0], src[d * 4 + 1], 0, false);
                    w     = __builtin_amdgcn_cvt_pk_fp8_f32(src[d * 4 + 2], src[d * 4 + 3], w, true);
                    outv[d] = (unsigned)w;
                }
                *(uvec4*)(P + (size_t)node * 256 + half * 128 + (tid & 7) * 16) = outv;
            }
        }
        __syncthreads();             // pack reads done before next half's Cs overwrite
    }
}

// ---- edge kernel: REGISTER-prefetch fp8 P -> add+silu -> fp8 W2 MFMA -> phi -> scatter ----
// Round-12: __launch_bounds__(256,3). The allocation table is now mapped:
//   (256,2): budget 256, arch cap 128, demand 80 fits -> 2 waves/SIMD, 117us [round 10]
//   (256,4): budget 128, arch cap 64,  demand ~100 SPILLS -> 179us        [round 11]
//   none:    high-occ target, arch 64, SPILLS -> 173us                    [round 9]
// Untested cell: (256,3) = budget 170, arch cap 84 (observed round 2). Current slim
// structure's measured arch demand is 80 <= 84 -> should fit with 3 waves/SIMD.
// (Round-2's (256,3) spill was the old ~140-reg structure.) Grid 768 (3/CU).
// Schedule byte-identical to round 10 (register single-buffer prefetch, verified).
__global__ __launch_bounds__(256, 3) void egnn_edge_p(
    const u8* __restrict__ P, const void* __restrict__ coord_diff,
    const void* __restrict__ edge_attr, const void* __restrict__ edge_index,
    const u16* __restrict__ w1lb, const void* __restrict__ b2,
    const void* __restrict__ W3, const u16* __restrict__ W2t,
    float* __restrict__ agg, int rep_mask)
{
    __shared__ __align__(16) u8  W2f8[16384];  // frag-ordered W2 (16 KB fp8), K-chunk-permuted
    __shared__ __align__(16) u16 w1ls[128];    // last W1 row (256 B)
    const int tid = threadIdx.x;
    #pragma unroll
    for (int i = 0; i < 8; ++i) {              // stage: f = t*512+ks*64+fh*32+fl, dst=f*8 bytes
        int f = i * 256 + tid;
        int t = f >> 9, ks = (f >> 6) & 7, fh = (f >> 5) & 1, fl = f & 31;
        // chunk for (ks,fh) is c = fh*8 + ks  (contiguous-per-lane K remap)
        svec8 v = *(const svec8*)(W2t + (t * 32 + fl) * 128 + fh * 64 + ks * 8);
        float x0 = bf2f((u16)v[0]), x1 = bf2f((u16)v[1]), x2 = bf2f((u16)v[2]), x3 = bf2f((u16)v[3]);
        float x4 = bf2f((u16)v[4]), x5 = bf2f((u16)v[5]), x6 = bf2f((u16)v[6]), x7 = bf2f((u16)v[7]);
        int w0 = __builtin_amdgcn_cvt_pk_fp8_f32(x0, x1, 0, false);
        w0     = __builtin_amdgcn_cvt_pk_fp8_f32(x2, x3, w0, true);
        int w1 = __builtin_amdgcn_cvt_pk_fp8_f32(x4, x5, 0, false);
        w1     = __builtin_amdgcn_cvt_pk_fp8_f32(x6, x7, w1, true);
        uvec2 wv2; wv2[0] = (unsigned)w0; wv2[1] = (unsigned)w1;
        *(uvec2*)(&W2f8[f * 8]) = wv2;
    }
    if (tid < 16) *(uvec4*)(&w1ls[tid * 8]) = *(const uvec4*)(w1lb + tid * 8);
    const int is_bf = detect_bf_w(edge_attr);
    const int is_i64 = detect_i64_w(edge_index);
    const int lane = tid & 63, wv = tid >> 6, l31 = lane & 31, hi = lane >> 5;

    float b2c[4], w3c[4];
    #pragma unroll
    for (int t = 0; t < 4; ++t) {
        int c = t * 32 + l31;
        b2c[t] = ldf(b2, c, is_bf);
        w3c[t] = ldf(W3, c, is_bf);
    }
    __syncthreads();                           // last barrier; main loop is wave-autonomous

    float* const aggw = agg + (size_t)(blockIdx.x & rep_mask) * AGG_STRIDE_F;

    // static output-row mapping for the tree-reduce result
    const int b0 = l31 & 1, bb1 = (l31 >> 1) & 1, bb2 = (l31 >> 2) & 1, bb3 = (l31 >> 3) & 1;
    const int rr = (b0 << 3) | (bb1 << 2) | (bb2 << 1) | bb3;   // bitrev4(l31&15)
    const int em = (rr & 3) + 8 * (rr >> 2) + 4 * hi;           // C-layout row within group

    const int wid = blockIdx.x * 4 + wv, nw = gridDim.x * 4;
    int g = wid;
    uvec4 pv1[4], pv2[4];
    int rowN = 0, colN = 0; float eaN = 0.0f, ea_cur = 0.0f;
    if (g < NGROUP) {   // prologue: idx(g) -> gather(g) into regs -> idx(g+nw)
        const int e = g * 32 + l31;
        const int row0 = ldi(edge_index, (size_t)e, is_i64);
        const int col0 = ldi(edge_index, (size_t)E_EDGES + e, is_i64);
        ea_cur = ldf(edge_attr, (size_t)e, is_bf);
        const u8* pr = P + (size_t)row0 * 256 + hi * 64;
        const u8* pc = P + (size_t)col0 * 256 + 128 + hi * 64;
        #pragma unroll
        for (int j = 0; j < 4; ++j) pv1[j] = *(const uvec4*)(pr + j * 16);
        #pragma unroll
        for (int j = 0; j < 4; ++j) pv2[j] = *(const uvec4*)(pc + j * 16);
        const int gn = g + nw;
        if (gn < NGROUP) {
            const int en = gn * 32 + l31;
            rowN = ldi(edge_index, (size_t)en, is_i64);
            colN = ldi(edge_index, (size_t)E_EDGES + en, is_i64);
            eaN  = ldf(edge_attr, (size_t)en, is_bf);
        }
    }
    while (g < NGROUP) {
        const int gn = g + nw;
        // ---- 1. convert pv -> af fp8 (pv registers die here) ----
        long long af8[8];
        #pragma unroll
        for (int ks = 0; ks < 8; ++ks) {
            const unsigned a0 = pv1[ks >> 1][(ks & 1) * 2];
            const unsigned a1 = pv1[ks >> 1][(ks & 1) * 2 + 1];
            const unsigned c0 = pv2[ks >> 1][(ks & 1) * 2];
            const unsigned c1 = pv2[ks >> 1][(ks & 1) * 2 + 1];
            float q1[8], q2[8];
            {
                fvec2 t0 = __builtin_amdgcn_cvt_pk_f32_fp8((int)a0, false);
                fvec2 t1 = __builtin_amdgcn_cvt_pk_f32_fp8((int)a0, true);
                fvec2 t2 = __builtin_amdgcn_cvt_pk_f32_fp8((int)a1, false);
                fvec2 t3 = __builtin_amdgcn_cvt_pk_f32_fp8((int)a1, true);
                q1[0] = t0[0]; q1[1] = t0[1]; q1[2] = t1[0]; q1[3] = t1[1];
                q1[4] = t2[0]; q1[5] = t2[1]; q1[6] = t3[0]; q1[7] = t3[1];
                fvec2 s0 = __builtin_amdgcn_cvt_pk_f32_fp8((int)c0, false);
                fvec2 s1 = __builtin_amdgcn_cvt_pk_f32_fp8((int)c0, true);
                fvec2 s2 = __builtin_amdgcn_cvt_pk_f32_fp8((int)c1, false);
                fvec2 s3 = __builtin_amdgcn_cvt_pk_f32_fp8((int)c1, true);
                q2[0] = s0[0]; q2[1] = s0[1]; q2[2] = s1[0]; q2[3] = s1[1];
                q2[4] = s2[0]; q2[5] = s2[1]; q2[6] = s3[0]; q2[7] = s3[1];
            }
            const uvec4 wl = *(const uvec4*)(&w1ls[(hi * 8 + ks) * 8]);
            float y[8];
            #pragma unroll
            for (int p = 0; p < 4; ++p) {
                const unsigned uw = wl[p];
                float xl = q1[2 * p]     + q2[2 * p]     + ea_cur * lo16(uw);
                float xh = q1[2 * p + 1] + q2[2 * p + 1] + ea_cur * hi16(uw);
                y[2 * p] = silu_fast(xl); y[2 * p + 1] = silu_fast(xh);
            }
            int w0 = __builtin_amdgcn_cvt_pk_fp8_f32(y[0], y[1], 0, false);
            w0     = __builtin_amdgcn_cvt_pk_fp8_f32(y[2], y[3], w0, true);
            int w1 = __builtin_amdgcn_cvt_pk_fp8_f32(y[4], y[5], 0, false);
            w1     = __builtin_amdgcn_cvt_pk_fp8_f32(y[6], y[7], w1, true);
            af8[ks] = (long long)(((unsigned long long)(unsigned)w1 << 32) | (unsigned)w0);
        }
        // ---- 2. issue next group's gathers into the SAME pv regs (pinned placement) ----
        __builtin_amdgcn_sched_barrier(0);
        if (gn < NGROUP) {
            const u8* pr = P + (size_t)rowN * 256 + hi * 64;
            const u8* pc = P + (size_t)colN * 256 + 128 + hi * 64;
            #pragma unroll
            for (int j = 0; j < 4; ++j) pv1[j] = *(const uvec4*)(pr + j * 16);
            #pragma unroll
            for (int j = 0; j < 4; ++j) pv2[j] = *(const uvec4*)(pc + j * 16);
        }
        __builtin_amdgcn_sched_barrier(0);
        // ---- 3. idx prefetch for g+2nw and scatter-side loads for current g ----
        int rowN2 = 0, colN2 = 0; float eaN2 = 0.0f;
        if (gn + nw < NGROUP) {
            const int en = (gn + nw) * 32 + l31;
            rowN2 = ldi(edge_index, (size_t)en, is_i64);
            colN2 = ldi(edge_index, (size_t)E_EDGES + en, is_i64);
            eaN2  = ldf(edge_attr, (size_t)en, is_bf);
        }
        const int eg = g * 32 + em;
        const int r2 = ldi(edge_index, (size_t)eg, is_i64);
        float cd0, cd1;
        if (l31 < 16) {
            cd0 = ldf(coord_diff, (size_t)eg * 3 + 0, is_bf);
            cd1 = ldf(coord_diff, (size_t)eg * 3 + 1, is_bf);
        } else {
            cd0 = ldf(coord_diff, (size_t)eg * 3 + 2, is_bf);
            cd1 = 0.0f;
        }
        // ---- 4. fp8 W2 MFMA + silu + W3 dot, per output strip ----
        float s[16];
        #pragma unroll
        for (int r = 0; r < 16; ++r) s[r] = 0.0f;
        #pragma unroll
        for (int t = 0; t < 4; ++t) {          // per-strip acc: 16 regs
            fvec16 acc = {};
            #pragma unroll
            for (int ks = 0; ks < 8; ++ks) {
                union { uvec2 u; long long l; } bu;
                bu.u = *(const uvec2*)(&W2f8[((t * 8 + ks) * 2 + hi) * 256 + l31 * 8]);
                acc = __builtin_amdgcn_mfma_f32_32x32x16_fp8_fp8(af8[ks], bu.l, acc, 0, 0, 0);
            }
            #pragma unroll
            for (int r = 0; r < 16; ++r)
                s[r] += silu_fast(acc[r] + b2c[t]) * w3c[t];
        }
        // ---- 5. halving-tree reduce: 16 rows over 32 lanes in 31 shuffles ----
        #pragma unroll
        for (int r = 0; r < 16; ++r) s[r] += __shfl_xor(s[r], 1);
        float w4[8];
        #pragma unroll
        for (int j = 0; j < 8; ++j) w4[j] = b0 ? s[j + 8] : s[j];
        #pragma unroll
        for (int j = 0; j < 8; ++j) w4[j] += __shfl_xor(w4[j], 2);
        float x4[4];
        #pragma unroll
        for (int j = 0; j < 4; ++j) x4[j] = bb1 ? w4[j + 4] : w4[j];
        #pragma unroll
        for (int j = 0; j < 4; ++j) x4[j] += __shfl_xor(x4[j], 4);
        float y2[2];
        y2[0] = bb2 ? x4[2] : x4[0];
        y2[1] = bb2 ? x4[3] : x4[1];
        y2[0] += __shfl_xor(y2[0], 8);
        y2[1] += __shfl_xor(y2[1], 8);
        float z = bb3 ? y2[1] : y2[0];
        z += __shfl_xor(z, 16);
        // ---- 6. scatter to XCD-private replica ----
        if (l31 < 16) {
            atomicAdd(&aggw[r2 * 3 + 0], cd0 * z);
            atomicAdd(&aggw[r2 * 3 + 1], cd1 * z);
        } else {
            atomicAdd(&aggw[r2 * 3 + 2], cd0 * z);
        }
        // ---- rotate pipeline state ----
        g = gn; ea_cur = eaN;
        rowN = rowN2; colN = colN2; eaN = eaN2;
    }
}

// ================= fallback (verified) when ws too small: writes replica 0 =================
__global__ __launch_bounds__(256, 2) void egnn_edge_kernel(
    const void* __restrict__ h, const void* __restrict__ coord_diff,
    const void* __restrict__ edge_attr, const void* __restrict__ edge_index,
    const void* __restrict__ W1, const void* __restrict__ b1,
    const void* __restrict__ b2, const void* __restrict__ W3,
    const u16* __restrict__ W1t, const u16* __restrict__ W2t,
    float* __restrict__ agg)
{
    __shared__ __align__(16) u16 Xs[BE * XS_STRIDE];
    __shared__ int   rows_s[BE];
    __shared__ int   cols_s[BE];
    __shared__ float ea_s[BE];
    __shared__ float b1_s[HID], b2_s[HID], w1l_s[HID], w3_s[HID];

    const int tid = threadIdx.x;
    const int e0  = blockIdx.x * BE;
    const int is_bf  = detect_bf_w(h);
    const int is_i64 = detect_i64_w(edge_index);

    if (tid < BE) {
        rows_s[tid] = ldi(edge_index, (size_t)(e0 + tid), is_i64);
        cols_s[tid] = ldi(edge_index, (size_t)(E_EDGES + e0 + tid), is_i64);
        ea_s[tid]   = ldf(edge_attr, (size_t)(e0 + tid), is_bf);
    }
    if (tid < HID) {
        b1_s[tid]  = ldf(b1, tid, is_bf);
        b2_s[tid]  = ldf(b2, tid, is_bf);
        w1l_s[tid] = ldf(W1, (size_t)256 * 128 + tid, is_bf);
        w3_s[tid]  = ldf(W3, tid, is_bf);
    }
    __syncthreads();
    {
        const int gg = tid >> 4, c = tid & 15;
        #pragma unroll
        for (int it = 0; it < 16; ++it) {
            int hr = it * 16 + gg;
            int e = hr >> 1, half = hr & 1;
            int src = half ? cols_s[e] : rows_s[e];
            svec8 v;
            if (is_bf) {
                v = *(const svec8*)((const u16*)h + (size_t)src * HID + c * 8);
            } else {
                const float* hf = (const float*)h + (size_t)src * HID + c * 8;
                float4 va = *(const float4*)hf;
                float4 vb = *(const float4*)(hf + 4);
                v[0] = (short)f2bf(va.x); v[1] = (short)f2bf(va.y);
                v[2] = (short)f2bf(va.z); v[3] = (short)f2bf(va.w);
                v[4] = (short)f2bf(vb.x); v[5] = (short)f2bf(vb.y);
                v[6] = (short)f2bf(vb.z); v[7] = (short)f2bf(vb.w);
            }
            *(svec8*)(&Xs[e * XS_STRIDE + half * 128 + c * 8]) = v;
        }
    }
    __syncthreads();
    const int lane = tid & 63;
    const int wv   = tid >> 6;
    const int l31  = lane & 31, hi = lane >> 5;
    const int col  = wv * 32 + l31;

    fvec16 acc[4] = {};
    for (int ks = 0; ks < 16; ++ks) {
        const int kk = ks * 16 + hi * 8;
        svec8 bfrag = *(const svec8*)(W1t + col * 256 + kk);
        #pragma unroll
        for (int mt = 0; mt < 4; ++mt) {
            svec8 afrag = *(const svec8*)(&Xs[(mt * 32 + l31) * XS_STRIDE + kk]);
            acc[mt] = __builtin_amdgcn_mfma_f32_32x32x16_bf16(afrag, bfrag, acc[mt], 0, 0, 0);
        }
    }
    __syncthreads();
    u16* Ys = Xs;
    #pragma unroll
    for (int mt = 0; mt < 4; ++mt)
        #pragma unroll
        for (int r = 0; r < 16; ++r) {
            int row = mt * 32 + (r & 3) + 8 * (r >> 2) + 4 * hi;
            float v = acc[mt][r] + ea_s[row] * w1l_s[col] + b1_s[col];
            Ys[row * YS_STRIDE + col] = f2bf(silu_f(v));
        }
    __syncthreads();
    fvec16 acc2[4] = {};
    for (int ks = 0; ks < 8; ++ks) {
        const int kk = ks * 16 + hi * 8;
        svec8 bfrag = *(const svec8*)(W2t + col * 128 + kk);
        #pragma unroll
        for (int mt = 0; mt < 4; ++mt) {
            svec8 afrag = *(const svec8*)(&Ys[(mt * 32 + l31) * YS_STRIDE + kk]);
            acc2[mt] = __builtin_amdgcn_mfma_f32_32x32x16_bf16(afrag, bfrag, acc2[mt], 0, 0, 0);
        }
    }
    __syncthreads();
    #pragma unroll
    for (int mt = 0; mt < 4; ++mt)
        #pragma unroll
        for (int r = 0; r < 16; ++r) {
            int row = mt * 32 + (r & 3) + 8 * (r >> 2) + 4 * hi;
            float v = acc2[mt][r] + b2_s[col];
            Ys[row * YS_STRIDE + col] = f2bf(silu_f(v));
        }
    __syncthreads();
    if (tid < BE) {
        const int e = tid;
        float phi = 0.0f;
        #pragma unroll
        for (int j = 0; j < 16; ++j) {
            svec8 x = *(const svec8*)(&Ys[e * YS_STRIDE + j * 8]);
            #pragma unroll
            for (int t = 0; t < 8; ++t)
                phi += bf2f((u16)x[t]) * w3_s[j * 8 + t];
        }
        const size_t ei = (size_t)(e0 + e);
        const int r = rows_s[e];
        atomicAdd(&agg[r * 3 + 0], ldf(coord_diff, ei * 3 + 0, is_bf) * phi);
        atomicAdd(&agg[r * 3 + 1], ldf(coord_diff, ei * 3 + 1, is_bf) * phi);
        atomicAdd(&agg[r * 3 + 2], ldf(coord_diff, ei * 3 + 2, is_bf) * phi);
    }
}

// ---- finalize: out = coord + (sum of replicas)/100, written in input float dtype ----
__global__ void finalize_kernel(const void* __restrict__ coord,
                                const float* __restrict__ agg,
                                void* __restrict__ out, int rep) {
    const int is_bf = detect_bf_w(coord);
    int i = blockIdx.x * blockDim.x + threadIdx.x;
    if (i < N_NODES * 3) {
        float a = 0.0f;
        for (int k = 0; k < rep; ++k) a += agg[(size_t)k * AGG_STRIDE_F + i];
        float v = ldf(coord, i, is_bf) + a * 0.01f;
        if (is_bf) ((u16*)out)[i] = f2bf(v);
        else       ((float*)out)[i] = v;
    }
}

extern "C" void kernel_launch(void* const* d_in, const int* in_sizes, int n_in,
                              void* d_out, int out_size, void* d_ws, size_t ws_size,
                              hipStream_t stream) {
    const void* h          = d_in[0];
    const void* coord      = d_in[1];
    const void* coord_diff = d_in[2];
    // d_in[3] = coord_cross (unused)
    const void* edge_attr  = d_in[4];
    const void* edge_index = d_in[5];
    const void* W1 = d_in[6];
    const void* b1 = d_in[7];
    const void* W2 = d_in[8];
    const void* b2 = d_in[9];
    const void* W3 = d_in[10];

    const size_t P_BYTES = (size_t)N_NODES * 256;           // 12,800,000
    const size_t NEED8 = 8ull * 600064 + 98560 + P_BYTES;   // ~17.7 MB
    const size_t NEED1 = 1ull * 600064 + 98560 + P_BYTES;   // ~13.5 MB

    const int rep = (ws_size >= NEED8) ? 8 : 1;
    char* ws    = (char*)d_ws;
    float* agg  = (float*)ws;                               // rep x 600064 B
    size_t a0   = (size_t)rep * 600064;
    u16* W1t    = (u16*)(ws + a0);                          // 65536 B
    u16* W2t    = (u16*)(ws + a0 + 65536);                  // 32768 B
    u16* w1lb   = (u16*)(ws + a0 + 98304);                  // 256 B
    u8* P       = (u8*)(ws + a0 + 98560);                   // 12,800,000 B

    // transpose_w also zeroes all agg replicas and self-detects dtype
    transpose_w<<<dim3(128), dim3(256), 0, stream>>>(W1, W2, W1t, W2t, w1lb, agg,
                                                     rep * AGG_STRIDE_F);

    if (ws_size >= (rep == 8 ? NEED8 : NEED1)) {
        precompute_p<<<dim3((N_NODES + 63) / 64), dim3(256), 0, stream>>>(
            h, b1, W1t, P);
        // 768 blocks = 3/CU under the (256,3) 170-reg budget (arch cap 84 >= demand 80)
        egnn_edge_p<<<dim3(768), dim3(256), 0, stream>>>(
            P, coord_diff, edge_attr, edge_index, w1lb, b2, W3, W2t, agg, rep - 1);
    } else {
        egnn_edge_kernel<<<dim3(E_EDGES / BE), dim3(256), 0, stream>>>(
            h, coord_diff, edge_attr, edge_index, W1, b1, b2, W3, W1t, W2t, agg);
    }
    finalize_kernel<<<dim3((N_NODES * 3 + 255) / 256), dim3(256), 0, stream>>>(
        coord, agg, d_out, rep);
}